// Round 1
// baseline (102.801 us; speedup 1.0000x reference)
//
#include <hip/hip_runtime.h>
#include <hip/hip_bf16.h>

typedef __attribute__((ext_vector_type(8))) short short8;   // 8 x bf16 (4 VGPR)
typedef __attribute__((ext_vector_type(4))) float f32x4;
typedef __attribute__((ext_vector_type(4))) int   i32x4;

#define KD 4096
#define ND 16384
#define MD 128

// round-to-nearest-even f32 -> bf16 bits
__device__ __forceinline__ ushort f2bf_rn(float f) {
    unsigned u = __float_as_uint(f);
    u += 0x7FFFu + ((u >> 16) & 1u);
    return (ushort)(u >> 16);
}

// exact for |v| <= 127: int -> f32 -> truncate to bf16 (low 16 bits of f32 are 0)
__device__ __forceinline__ ushort i2bf(int v) {
    return (ushort)(__float_as_uint((float)v) >> 16);
}

// Pack x[128][4096] f32 into bf16 MFMA A-fragment order:
// xp[kb][mt][lane][j] = x[16*mt + (lane&15)][32*kb + 8*(lane>>4) + j]
// 128*8*64*8 ushort = 1 MiB in d_ws.
__global__ __launch_bounds__(256) void pack_x_kernel(const float* __restrict__ x,
                                                     ushort* __restrict__ xp) {
    int tid  = blockIdx.x * 256 + threadIdx.x;   // 0..65535
    int lane = tid & 63;
    int mt   = (tid >> 6) & 7;
    int kb   = tid >> 9;                          // 0..127
    int m = (mt << 4) + (lane & 15);
    int k = (kb << 5) + ((lane >> 4) << 3);
    const f32x4* src = reinterpret_cast<const f32x4*>(x + (size_t)m * KD + k);
    f32x4 a = src[0];
    f32x4 b = src[1];
    short8 v;
    v[0] = (short)f2bf_rn(a[0]); v[1] = (short)f2bf_rn(a[1]);
    v[2] = (short)f2bf_rn(a[2]); v[3] = (short)f2bf_rn(a[3]);
    v[4] = (short)f2bf_rn(b[0]); v[5] = (short)f2bf_rn(b[1]);
    v[6] = (short)f2bf_rn(b[2]); v[7] = (short)f2bf_rn(b[3]);
    *reinterpret_cast<short8*>(xp + (size_t)tid * 8) = v;
}

// Each wave owns 16 output columns (n0..n0+15), full K, all 8 m-tiles.
// Weights streamed HBM->reg (dwordx4 x2 per k-step), converted to bf16 in-reg.
__global__ __launch_bounds__(256) void gemm_kernel(const int* __restrict__ w,
                                                   const ushort* __restrict__ xp,
                                                   const float* __restrict__ scales,
                                                   const float* __restrict__ bias,
                                                   float* __restrict__ out) {
    const int lane  = threadIdx.x & 63;
    const int wv    = threadIdx.x >> 6;
    const int nt    = blockIdx.x * 4 + wv;        // 0..1023
    const int n0    = nt << 4;
    const int ncol  = n0 + (lane & 15);
    const int khalf = (lane >> 4) << 3;           // 0,8,16,24

    const int* wp = w + (size_t)ncol * KD + khalf;

    f32x4 acc[8];
#pragma unroll
    for (int i = 0; i < 8; ++i) acc[i] = (f32x4){0.f, 0.f, 0.f, 0.f};

    // prime the prefetch pipeline
    i32x4 w0 = *reinterpret_cast<const i32x4*>(wp);
    i32x4 w1 = *reinterpret_cast<const i32x4*>(wp + 4);

    const ushort* xbase = xp + (size_t)lane * 8;

    for (int kb = 0; kb < 128; ++kb) {
        // prefetch next k-tile (clamped at the end: redundant reload, in-bounds)
        const int* wn = wp + ((kb < 127) ? 32 : 0);
        i32x4 nw0 = *reinterpret_cast<const i32x4*>(wn);
        i32x4 nw1 = *reinterpret_cast<const i32x4*>(wn + 4);

        short8 bfrag;
        bfrag[0] = (short)i2bf(w0[0]);
        bfrag[1] = (short)i2bf(w0[1]);
        bfrag[2] = (short)i2bf(w0[2]);
        bfrag[3] = (short)i2bf(w0[3]);
        bfrag[4] = (short)i2bf(w1[0]);
        bfrag[5] = (short)i2bf(w1[1]);
        bfrag[6] = (short)i2bf(w1[2]);
        bfrag[7] = (short)i2bf(w1[3]);

        const ushort* xk = xbase + (size_t)kb * 4096;  // (kb*8+mt)*512 + lane*8
#pragma unroll
        for (int mt = 0; mt < 8; ++mt) {
            short8 afrag = *reinterpret_cast<const short8*>(xk + (size_t)mt * 512);
            acc[mt] = __builtin_amdgcn_mfma_f32_16x16x32_bf16(afrag, bfrag, acc[mt], 0, 0, 0);
        }

        wp = wn;
        w0 = nw0; w1 = nw1;
    }

    // epilogue: out[m][n] = acc * scale[n]/127 + bias[n]
    // C/D layout (16x16x32 bf16): col = lane&15, row = (lane>>4)*4 + reg
    const float s  = scales[ncol] * (1.0f / 127.0f);
    const float bs = bias[ncol];
    const int rbase = (lane >> 4) << 2;
#pragma unroll
    for (int mt = 0; mt < 8; ++mt) {
#pragma unroll
        for (int r = 0; r < 4; ++r) {
            int m = (mt << 4) + rbase + r;
            out[(size_t)m * ND + ncol] = acc[mt][r] * s + bs;
        }
    }
}

extern "C" void kernel_launch(void* const* d_in, const int* in_sizes, int n_in,
                              void* d_out, int out_size, void* d_ws, size_t ws_size,
                              hipStream_t stream) {
    const float* x      = (const float*)d_in[0];
    const int*   w      = (const int*)d_in[1];     // int8 promoted to int32 by harness
    const float* scales = (const float*)d_in[2];
    const float* bias   = (const float*)d_in[3];
    float* out = (float*)d_out;
    ushort* xp = (ushort*)d_ws;                    // 1 MiB bf16 packed x

    pack_x_kernel<<<MD * KD / (8 * 256), 256, 0, stream>>>(x, xp);
    gemm_kernel<<<ND / 64, 256, 0, stream>>>(w, xp, scales, bias, out);
}

// Round 3
// 68.928 us; speedup vs baseline: 1.4914x; 1.4914x over previous
//
#include <hip/hip_runtime.h>
#include <hip/hip_bf16.h>

typedef __attribute__((ext_vector_type(8))) short short8;   // 8 x bf16 (4 VGPR)
typedef __attribute__((ext_vector_type(4))) float f32x4;
typedef __attribute__((ext_vector_type(4))) int   i32x4;

#define KD 4096
#define ND 16384
#define MD 128

// round-to-nearest-even f32 -> bf16 bits
__device__ __forceinline__ ushort f2bf_rn(float f) {
    unsigned u = __float_as_uint(f);
    u += 0x7FFFu + ((u >> 16) & 1u);
    return (ushort)(u >> 16);
}

// exact for |v| <= 127: int -> f32 -> truncate to bf16 (small ints have zero low mantissa bits)
__device__ __forceinline__ ushort i2bf(int v) {
    return (ushort)(__float_as_uint((float)v) >> 16);
}

// Pack x[128][4096] f32 into bf16 MFMA A-fragment order (identical to round 1, verified):
// xp[kb][mt][lane][j] = x[16*mt + (lane&15)][32*kb + 8*(lane>>4) + j]   (1 MiB)
__global__ __launch_bounds__(256) void pack_x_kernel(const float* __restrict__ x,
                                                     ushort* __restrict__ xp) {
    int tid  = blockIdx.x * 256 + threadIdx.x;   // 0..65535
    int lane = tid & 63;
    int mt   = (tid >> 6) & 7;
    int kb   = tid >> 9;                          // 0..127
    int m = (mt << 4) + (lane & 15);
    int k = (kb << 5) + ((lane >> 4) << 3);
    const f32x4* src = reinterpret_cast<const f32x4*>(x + (size_t)m * KD + k);
    f32x4 a = src[0];
    f32x4 b = src[1];
    short8 v;
    v[0] = (short)f2bf_rn(a[0]); v[1] = (short)f2bf_rn(a[1]);
    v[2] = (short)f2bf_rn(a[2]); v[3] = (short)f2bf_rn(a[3]);
    v[4] = (short)f2bf_rn(b[0]); v[5] = (short)f2bf_rn(b[1]);
    v[6] = (short)f2bf_rn(b[2]); v[7] = (short)f2bf_rn(b[3]);
    *reinterpret_cast<short8*>(xp + (size_t)tid * 8) = v;
}

#define GLOAD_LDS16(g, l)                                                        \
    __builtin_amdgcn_global_load_lds((const __attribute__((address_space(1))) void*)(g), \
                                     (__attribute__((address_space(3))) void*)(l), 16, 0, 0)

// Block: 64 output cols x 64 output rows (m-half) x full K=4096.
// Grid 512 = 256 n-groups x 2 m-halves; pair (nb, nb+256) shares W cols on the same XCD.
// LDS: A dbuf 2x8KiB + W dbuf 2x16KiB = 48 KiB -> 2 blocks/CU.
// Phase (verified 2-phase template): STAGE(t+1) ; COMPUTE(t) ; __syncthreads().
__global__ __launch_bounds__(256, 2) void gemm_kernel(const int* __restrict__ wgt,
                                                      const ushort* __restrict__ xp,
                                                      const float* __restrict__ scales,
                                                      const float* __restrict__ bias,
                                                      float* __restrict__ out) {
    __shared__ __align__(16) char lds[49152];   // A0[0,8K) A1[8K,16K) W0[16K,32K) W1[32K,48K)

    const int tid  = threadIdx.x;
    const int lane = tid & 63;
    const int w    = tid >> 6;          // wave 0..3 -> col group [16w,16w+16)
    const int nb   = blockIdx.x & 255;  // n-group
    const int h    = blockIdx.x >> 8;   // m-half
    const int n0   = nb << 6;
    const int cl   = lane & 15;
    const int cq   = lane >> 4;         // k-quarter 0..3

    // ---- A staging source (per-lane, advances by 16 KiB per chunk) ----
    // chunk t, issue j: src = xp + (2t+j)*8192 + h*4096 + w*1024 + lane*16
    const char* asrc = (const char*)xp + (h << 12) + (w << 10) + (lane << 4);

    // ---- W staging sources: issue _i covers cols c = 16w + 4_i + cq ----
    // pre-swizzled source so the LINEAR gload_lds dest realizes layout
    // off(c,k) = c*256 + ((4k) ^ ((c&7)<<4))  [verified bijective per col]
    const int* wsrc0;
    const int* wsrc1;
    const int* wsrc2;
    const int* wsrc3;
    {
        int c0 = (w << 4) + 0  + cq;
        int c1 = (w << 4) + 4  + cq;
        int c2 = (w << 4) + 8  + cq;
        int c3 = (w << 4) + 12 + cq;
        wsrc0 = wgt + (size_t)(n0 + c0) * KD + ((cl ^ (c0 & 7)) << 2);
        wsrc1 = wgt + (size_t)(n0 + c1) * KD + ((cl ^ (c1 & 7)) << 2);
        wsrc2 = wgt + (size_t)(n0 + c2) * KD + ((cl ^ (c2 & 7)) << 2);
        wsrc3 = wgt + (size_t)(n0 + c3) * KD + ((cl ^ (c3 & 7)) << 2);
    }

    f32x4 acc[4];
#pragma unroll
    for (int i = 0; i < 4; ++i) acc[i] = (f32x4){0.f, 0.f, 0.f, 0.f};

    // LDS dest bases (wave-uniform; HW adds lane*16)
    char* dA = lds + (w << 10);                       // + b*8192 + j*4096
    char* dW = lds + 16384 + (w << 12);               // + b*16384 + _i*1024

#define STAGE(t, b) do {                                                        \
        const char* _as = asrc + (size_t)(t) * 16384;                           \
        GLOAD_LDS16(_as,        dA + (b) * 8192);                               \
        GLOAD_LDS16(_as + 8192, dA + (b) * 8192 + 4096);                        \
        const int _k0 = (t) * 64;                                               \
        GLOAD_LDS16(wsrc0 + _k0, dW + (b) * 16384);                             \
        GLOAD_LDS16(wsrc1 + _k0, dW + (b) * 16384 + 1024);                      \
        GLOAD_LDS16(wsrc2 + _k0, dW + (b) * 16384 + 2048);                      \
        GLOAD_LDS16(wsrc3 + _k0, dW + (b) * 16384 + 3072);                      \
    } while (0)

    // compute-side read bases
    const char* rA = lds + (lane << 4);                         // + b*8192 + kbl*4096 + m*1024
    const char* rW = lds + 16384 + (((w << 4) + cl) << 8);      // + b*16384 + inner
    const int sw   = (cl & 7) << 4;
    const int q32  = cq << 5;

#define COMPUTE(b) do {                                                         \
        _Pragma("unroll")                                                       \
        for (int _kbl = 0; _kbl < 2; ++_kbl) {                                  \
            int _ib = ((_kbl << 7) + q32) ^ sw;                                 \
            i32x4 _lo = *reinterpret_cast<const i32x4*>(rW + (b) * 16384 + _ib);        \
            i32x4 _hi = *reinterpret_cast<const i32x4*>(rW + (b) * 16384 + (_ib ^ 16)); \
            short8 _bf;                                                         \
            _bf[0] = (short)i2bf(_lo[0]); _bf[1] = (short)i2bf(_lo[1]);         \
            _bf[2] = (short)i2bf(_lo[2]); _bf[3] = (short)i2bf(_lo[3]);         \
            _bf[4] = (short)i2bf(_hi[0]); _bf[5] = (short)i2bf(_hi[1]);         \
            _bf[6] = (short)i2bf(_hi[2]); _bf[7] = (short)i2bf(_hi[3]);         \
            const char* _ab = rA + (b) * 8192 + _kbl * 4096;                    \
            _Pragma("unroll")                                                   \
            for (int _m = 0; _m < 4; ++_m) {                                    \
                short8 _af = *reinterpret_cast<const short8*>(_ab + _m * 1024); \
                acc[_m] = __builtin_amdgcn_mfma_f32_16x16x32_bf16(_af, _bf, acc[_m], 0, 0, 0); \
            }                                                                   \
        }                                                                       \
    } while (0)

    // ---- main loop: 64 chunks of K=64 ----
    STAGE(0, 0);
    __syncthreads();
    for (int t = 0; t < 63; ++t) {
        const int cb = t & 1;
        STAGE(t + 1, cb ^ 1);
        COMPUTE(cb);
        __syncthreads();
    }
    COMPUTE(1);

    // ---- epilogue: scale + bias, direct store (block owns its 64x64 tile) ----
    const int ncol = n0 + (w << 4) + cl;
    const float s  = scales[ncol] * (1.0f / 127.0f);
    const float bv = bias[ncol];
    const int rb = cq << 2;
#pragma unroll
    for (int m = 0; m < 4; ++m) {
#pragma unroll
        for (int r = 0; r < 4; ++r) {
            int mg = (h << 6) + (m << 4) + rb + r;
            out[(size_t)mg * ND + ncol] = acc[m][r] * s + bv;
        }
    }
#undef STAGE
#undef COMPUTE
}

extern "C" void kernel_launch(void* const* d_in, const int* in_sizes, int n_in,
                              void* d_out, int out_size, void* d_ws, size_t ws_size,
                              hipStream_t stream) {
    const float* x      = (const float*)d_in[0];
    const int*   wgt    = (const int*)d_in[1];     // int8 promoted to int32 by harness
    const float* scales = (const float*)d_in[2];
    const float* bias   = (const float*)d_in[3];
    float* out = (float*)d_out;
    ushort* xp = (ushort*)d_ws;                    // 1 MiB bf16 packed x

    pack_x_kernel<<<MD * KD / (8 * 256), 256, 0, stream>>>(x, xp);
    gemm_kernel<<<512, 256, 0, stream>>>(wgt, xp, scales, bias, out);
}